// Round 6
// baseline (317.123 us; speedup 1.0000x reference)
//
#include <hip/hip_runtime.h>

#define NBINS 30
#define NCELL 900            // 30*30
#define HWORDS (16*NCELL)    // 14400 cells per matrix histogram set
#define PWORDS (HWORDS/2)    // 7200 packed u32 (2 x u16 cells) per matrix
#define G_MM  2048           // legacy k_minmax grid
#define NCH   512            // max slot count (ws sizing / legacy path)
#define CG    16             // copy-groups for slot merge

typedef unsigned int u32;

// ws u32 layout:
//  [0] ymin key  [1] ymax key  (coop path: monotone u32 keys; legacy: plain f32)
//  [2..17] umin  [18..33] smin  [34..49] umax  [50..65] smax
//  [68..69] double lpt_sum   [70..71] double mi2d_sum
//  [72..73] double mi_us_sum [74] finalize counter [76] barrier release flag
//  [BCTR_OFF + b], b=0..1023 : per-block barrier arrival counters (1 word each)
//  [PB_OFF ..)  : legacy k_minmax partials pb[v*G_MM + b]
//  [HS_OFF ..)  : summed histograms (legacy fallback only)
//  [GH_OFF ..)  : hist slots: packed nch x {u:7200, s:7200} (or legacy unpacked copies)
//  [PT ..)      : stage-1 partials CG x 28800 u32
#define BCTR_OFF 128
#define PB_OFF 4096
#define HS_OFF (PB_OFF + 68*G_MM)
#define GH_OFF (HS_OFF + 2*HWORDS)

// ---- float <-> order-preserving u32 key (for atomicMin/Max on floats) ----
__device__ inline u32 fkey(float f) {
    u32 b = __float_as_uint(f);
    return (b & 0x80000000u) ? ~b : (b | 0x80000000u);
}
__device__ inline float funkey(u32 k) {
    u32 b = (k & 0x80000000u) ? (k ^ 0x80000000u) : ~k;
    return __uint_as_float(b);
}

// ---- grid barrier v3: store-only entry, parallel detection, flag release ----
// Entry: block bid release-stores `epoch` to its OWN counter word (no RMW).
// Detection: block 0's 512 threads sweep all G counters in parallel.
// Release: one flag store; waiters poll flag at s_sleep(32) (~0.85us).
__device__ inline void gbar(u32* W, int bid, int G, u32 epoch) {
    __syncthreads();
    if (threadIdx.x == 0) {
        __threadfence();      // prior global writes visible before signaling
        __hip_atomic_store(&W[BCTR_OFF + bid], epoch,
                           __ATOMIC_RELEASE, __HIP_MEMORY_SCOPE_AGENT);
    }
    if (bid == 0) {
        __shared__ int ok;
        for (;;) {
            if (threadIdx.x == 0) ok = 1;
            __syncthreads();
            int t = threadIdx.x;
            u32 a = (t < G) ? __hip_atomic_load(&W[BCTR_OFF + t],
                        __ATOMIC_RELAXED, __HIP_MEMORY_SCOPE_AGENT) : epoch;
            u32 b = (512 + t < G) ? __hip_atomic_load(&W[BCTR_OFF + 512 + t],
                        __ATOMIC_RELAXED, __HIP_MEMORY_SCOPE_AGENT) : epoch;
            if (a < epoch || b < epoch) ok = 0;    // benign same-value race
            __syncthreads();
            if (ok) break;
            __builtin_amdgcn_s_sleep(1);
        }
        if (threadIdx.x == 0) {
            __threadfence();
            __hip_atomic_store(&W[76], epoch,
                               __ATOMIC_RELEASE, __HIP_MEMORY_SCOPE_AGENT);
        }
    } else if (threadIdx.x == 0) {
        while (__hip_atomic_load(&W[76], __ATOMIC_RELAXED,
                                 __HIP_MEMORY_SCOPE_AGENT) < epoch)
            __builtin_amdgcn_s_sleep(32);
        __threadfence();
    }
    __syncthreads();
}

// ---- tiny per-iteration state init (coop path) ----
__global__ void k_init0(u32* W) {
    int t = threadIdx.x;
    if (t < 16) { W[2 + t] = 0xFFFFFFFFu; W[18 + t] = 0xFFFFFFFFu; W[34 + t] = 0u; W[50 + t] = 0u; }
    else if (t == 16) { W[0] = 0xFFFFFFFFu; W[1] = 0u; }
    else if (t == 17) {
        ((double*)(W + 68))[0] = 0.0;
        ((double*)(W + 70))[0] = 0.0;
        ((double*)(W + 72))[0] = 0.0;
    } else if (t == 18) { W[74] = 0u; W[76] = 0u; }
    for (int i = t; i < 1024; i += 512) W[BCTR_OFF + i] = 0u;
}

// =====================================================================
// Cooperative all-in-one kernel: minmax -> [bar] -> hist -> [bar] ->
// slot-merge -> [bar] -> MI + mi_us + finalize.  Grid = 2*nch blocks x 512.
// =====================================================================
__global__ __launch_bounds__(512, 4) void k_all(
    const float* __restrict__ yt, const float* __restrict__ yp,
    const float* __restrict__ uv, const float* __restrict__ sv,
    int N, u32* __restrict__ W, u32* __restrict__ gh, u32* __restrict__ part,
    float* __restrict__ out)
{
    const int G = gridDim.x;
    const int nch = G >> 1;
    const int t = threadIdx.x;
    const int bid = blockIdx.x;

    __shared__ u32 smem[PWORDS];        // hist (phase 1), reused as C[] (phase 3)
    __shared__ float ex[16][32];
    __shared__ float ey[32];
    __shared__ float emn[16], esc[16];
    __shared__ float yp0[2];
    __shared__ float LUmn[128], LUmx[128], LSmn[128], LSmx[128];   // 8 waves x 16
    __shared__ float LY[8][3];
    __shared__ double red[8];
    __shared__ double mis[16];

    // ---------------- phase 0: min/max + y min/max + L_PT ----------------
    {
        const float INF = __builtin_inff();
        float umn[4], umx[4], smn[4], smx[4];
#pragma unroll
        for (int k = 0; k < 4; k++) { umn[k] = INF; umx[k] = -INF; smn[k] = INF; smx[k] = -INF; }

        size_t nv4 = (size_t)N * 4;
        size_t per = ((nv4 + (size_t)G * 512 - 1) / ((size_t)G * 512)) * 512;
        size_t beg = (size_t)bid * per;
        size_t end = beg + per;
        if (beg > nv4) beg = nv4;
        if (end > nv4) end = nv4;
        const float4* u4 = (const float4*)uv;
        const float4* s4 = (const float4*)sv;

        auto accU = [&](float4 a) {
            umn[0] = fminf(umn[0], a.x); umx[0] = fmaxf(umx[0], a.x);
            umn[1] = fminf(umn[1], a.y); umx[1] = fmaxf(umx[1], a.y);
            umn[2] = fminf(umn[2], a.z); umx[2] = fmaxf(umx[2], a.z);
            umn[3] = fminf(umn[3], a.w); umx[3] = fmaxf(umx[3], a.w);
        };
        auto accS = [&](float4 b) {
            smn[0] = fminf(smn[0], b.x); smx[0] = fmaxf(smx[0], b.x);
            smn[1] = fminf(smn[1], b.y); smx[1] = fmaxf(smx[1], b.y);
            smn[2] = fminf(smn[2], b.z); smx[2] = fmaxf(smx[2], b.z);
            smn[3] = fminf(smn[3], b.w); smx[3] = fmaxf(smx[3], b.w);
        };

        float ymn = INF, ymx = -INF, lpt = 0.0f;
        {
            size_t n2 = (size_t)N >> 1;
            size_t gid = (size_t)bid * 512 + t;
            size_t ystr = (size_t)G * 512;
            const float2* yp2 = (const float2*)yp;
            const float2* yt2 = (const float2*)yt;
            for (size_t q = gid; q < n2; q += ystr) {
                float2 a = yp2[q], b = yt2[q];
                ymn = fminf(ymn, fminf(a.x, a.y));
                ymx = fmaxf(ymx, fmaxf(a.x, a.y));
                lpt += fabsf(b.x - a.x) + fabsf(b.y - a.y);
            }
            if ((N & 1) && gid == 0) {
                float y = yp[N - 1];
                ymn = fminf(ymn, y); ymx = fmaxf(ymx, y);
                lpt += fabsf(yt[N - 1] - y);
            }
        }

        size_t i = beg + t;
        size_t nb = (end > beg) ? (end - beg) / 2048 : 0;
        if (nb && i + 1536 < end) {
            float4 u0 = u4[i], u1 = u4[i + 512], u2 = u4[i + 1024], u3 = u4[i + 1536];
            float4 s0 = s4[i], s1 = s4[i + 512], s2 = s4[i + 1024], s3 = s4[i + 1536];
            i += 2048;
            for (size_t b = 1; b < nb; b++, i += 2048) {
                float4 a0 = u4[i], a1 = u4[i + 512], a2 = u4[i + 1024], a3 = u4[i + 1536];
                float4 b0 = s4[i], b1 = s4[i + 512], b2 = s4[i + 1024], b3 = s4[i + 1536];
                accU(u0); accU(u1); accU(u2); accU(u3);
                accS(s0); accS(s1); accS(s2); accS(s3);
                u0 = a0; u1 = a1; u2 = a2; u3 = a3;
                s0 = b0; s1 = b1; s2 = b2; s3 = b3;
            }
            accU(u0); accU(u1); accU(u2); accU(u3);
            accS(s0); accS(s1); accS(s2); accS(s3);
        }
        for (; i < end; i += 512) { accU(u4[i]); accS(s4[i]); }

        // wave reduce keyed by lane&3
#pragma unroll
        for (int m = 4; m < 64; m <<= 1) {
#pragma unroll
            for (int k = 0; k < 4; k++) {
                umn[k] = fminf(umn[k], __shfl_xor(umn[k], m));
                umx[k] = fmaxf(umx[k], __shfl_xor(umx[k], m));
                smn[k] = fminf(smn[k], __shfl_xor(smn[k], m));
                smx[k] = fmaxf(smx[k], __shfl_xor(smx[k], m));
            }
        }
#pragma unroll
        for (int m = 1; m < 64; m <<= 1) {
            ymn = fminf(ymn, __shfl_xor(ymn, m));
            ymx = fmaxf(ymx, __shfl_xor(ymx, m));
            lpt += __shfl_xor(lpt, m);
        }

        int wave = t >> 6, lane = t & 63;
        if (lane < 4) {
#pragma unroll
            for (int k = 0; k < 4; k++) {
                LUmn[wave * 16 + lane * 4 + k] = umn[k];
                LUmx[wave * 16 + lane * 4 + k] = umx[k];
                LSmn[wave * 16 + lane * 4 + k] = smn[k];
                LSmx[wave * 16 + lane * 4 + k] = smx[k];
            }
        }
        if (lane == 0) { LY[wave][0] = ymn; LY[wave][1] = ymx; LY[wave][2] = lpt; }
        __syncthreads();
        if (t < 16) {
            float a = LUmn[t], b = LSmn[t], c = LUmx[t], d = LSmx[t];
#pragma unroll
            for (int w = 1; w < 8; w++) {
                a = fminf(a, LUmn[w * 16 + t]); b = fminf(b, LSmn[w * 16 + t]);
                c = fmaxf(c, LUmx[w * 16 + t]); d = fmaxf(d, LSmx[w * 16 + t]);
            }
            atomicMin(&W[2 + t], fkey(a));
            atomicMin(&W[18 + t], fkey(b));
            atomicMax(&W[34 + t], fkey(c));
            atomicMax(&W[50 + t], fkey(d));
        } else if (t == 16) {
            float v = LY[0][0];
#pragma unroll
            for (int w = 1; w < 8; w++) v = fminf(v, LY[w][0]);
            atomicMin(&W[0], fkey(v));
        } else if (t == 17) {
            float v = LY[0][1];
#pragma unroll
            for (int w = 1; w < 8; w++) v = fmaxf(v, LY[w][1]);
            atomicMax(&W[1], fkey(v));
        } else if (t == 18) {
            double s = 0.0;
#pragma unroll
            for (int w = 0; w < 8; w++) s += (double)LY[w][2];
            atomicAdd((double*)(W + 68), s);
        }
    }
    gbar(W, bid, G, 1u);

    // ---------------- phase 1: 2-D histograms into private packed slot ----------------
    {
        int mat = (bid >= nch) ? 1 : 0;
        int chunk = bid - mat * nch;

        for (int i = t; i < PWORDS; i += 512) smem[i] = 0;
        if (t < 16) {
            float mn = funkey(W[2 + mat * 16 + t]);
            float mx = funkey(W[34 + mat * 16 + t]);
            float step = (mx - mn) / 30.0f;
            for (int m = 0; m < 31; m++) ex[t][m] = __fadd_rn(__fmul_rn((float)m, step), mn);
            ex[t][30] = mx;
            emn[t] = mn;
            esc[t] = (mx > mn) ? 30.0f / (mx - mn) : 0.0f;
        } else if (t == 16) {
            float mn = funkey(W[0]), mx = funkey(W[1]);
            float step = (mx - mn) / 30.0f;
            for (int m = 0; m < 31; m++) ey[m] = __fadd_rn(__fmul_rn((float)m, step), mn);
            ey[30] = mx;
            yp0[0] = mn;
            yp0[1] = (mx > mn) ? 30.0f / (mx - mn) : 0.0f;
        }
        __syncthreads();

        float ymn = yp0[0], ysc = yp0[1];
        const float* src = mat ? sv : uv;
        int rpb = (N + nch - 1) / nch;
        int r0 = chunk * rpb;
        int r1 = r0 + rpb; if (r1 > N) r1 = N;

        auto process = [&](float y, float4 q0, float4 q1, float4 q2, float4 q3) {
            int yb = (int)__fmul_rn(__fsub_rn(y, ymn), ysc);
            if (yb > 29) yb = 29;
            if (y < ey[yb]) yb--;
            if (yb != 29 && y >= ey[yb + 1]) yb++;
            float v[16] = {q0.x, q0.y, q0.z, q0.w, q1.x, q1.y, q1.z, q1.w,
                           q2.x, q2.y, q2.z, q2.w, q3.x, q3.y, q3.z, q3.w};
#pragma unroll
            for (int j = 0; j < 16; j++) {
                float vv = v[j];
                int b = (int)__fmul_rn(__fsub_rn(vv, emn[j]), esc[j]);
                if (b > 29) b = 29;
                if (vv < ex[j][b]) b--;
                if (b != 29 && vv >= ex[j][b + 1]) b++;
                u32 idx = (u32)(j * NCELL + b * NBINS + yb);
                atomicAdd(&smem[idx >> 1], 1u << ((idx & 1) * 16));
            }
        };

        int row = r0 + t;
        if (row < r1) {
            const float4* p = (const float4*)(src + (size_t)row * 16);
            float4 c0 = p[0], c1 = p[1], c2 = p[2], c3 = p[3];
            float yc = yp[row];
            for (int nr = row + 512; nr < r1; nr += 512) {
                const float4* np = (const float4*)(src + (size_t)nr * 16);
                float4 d0 = np[0], d1 = np[1], d2 = np[2], d3 = np[3];
                float yn = yp[nr];
                process(yc, c0, c1, c2, c3);
                c0 = d0; c1 = d1; c2 = d2; c3 = d3; yc = yn;
            }
            process(yc, c0, c1, c2, c3);
        }
        __syncthreads();

        u32* dst = gh + ((size_t)chunk * 2 + mat) * PWORDS;
        for (int i = t; i < PWORDS; i += 512) dst[i] = smem[i];
    }
    gbar(W, bid, G, 2u);

    // ---------------- phase 2: slot merge (stage 1) ----------------
    {
        int spc = nch / CG;                   // slots per copy-group
        int total = CG * 2 * PWORDS;          // 230400 items
        for (int w = bid * 512 + t; w < total; w += G * 512) {
            int cg = w / (2 * PWORDS);
            int f = w - cg * (2 * PWORDS);
            const u32* p = gh + (size_t)(cg * spc) * (2 * PWORDS) + f;
            u32 lo = 0, hi = 0;
            for (int s = 0; s < spc; s++) {
                u32 x = p[(size_t)s * (2 * PWORDS)];
                lo += x & 0xFFFFu; hi += x >> 16;
            }
            int m2 = f / PWORDS, ii = f - m2 * PWORDS;
            u32* dst = part + (size_t)cg * (2 * HWORDS) + (size_t)m2 * HWORDS + 2 * ii;
            dst[0] = lo; dst[1] = hi;
        }
    }
    gbar(W, bid, G, 3u);

    // ---------------- phase 3: MI (blocks 0..31), mi_us (block 32) ----------------
    if (bid < 32) {
        float* C = (float*)smem;
        float* rsums = C + NCELL;
        float* csums = C + NCELL + 32;
        int mat = bid >> 4, col = bid & 15;
        const u32* src = part + (size_t)mat * HWORDS + (size_t)col * NCELL;
        for (int c = t; c < NCELL; c += 512) {
            u32 a = 0;
#pragma unroll
            for (int cg = 0; cg < CG; cg++) a += src[(size_t)cg * (2 * HWORDS) + c];
            C[c] = (float)a;
        }
        __syncthreads();
        if (t < NBINS) {
            float s = 0;
            for (int j = 0; j < NBINS; j++) s += C[t * NBINS + j];
            rsums[t] = s;
        } else if (t >= 32 && t < 32 + NBINS) {
            int j = t - 32;
            float s = 0;
            for (int i = 0; i < NBINS; i++) s += C[i * NBINS + j];
            csums[j] = s;
        }
        __syncthreads();

        const float n = (float)N;
        double acc = 0.0;
        for (int c = t; c < NCELL; c += 512) {
            int i = c / NBINS, j = c % NBINS;
            float pxy = (C[c] > 0.0f) ? (C[c] / n) : 1e-10f;
            float px = (rsums[i] > 0.0f) ? (rsums[i] / n) : 1e-10f;
            float py = (csums[j] > 0.0f) ? (csums[j] / n) : 1e-10f;
            acc += (double)(pxy * logf(pxy / (px * py)));
        }
#pragma unroll
        for (int o = 32; o > 0; o >>= 1) acc += __shfl_xor(acc, o);
        int wid = t >> 6;
        if ((t & 63) == 0) red[wid] = acc;
        __syncthreads();
        if (t == 0) {
            double tt = 0.0;
#pragma unroll
            for (int w = 0; w < 8; w++) tt += red[w];
            atomicAdd((double*)(W + 70), tt);
        }
    } else if (bid == 32) {
        if (t < 16) {
            float uval[16], sval[16];
#pragma unroll
            for (int k = 0; k < 16; k++) { uval[k] = uv[t * 16 + k]; sval[k] = sv[t * 16 + k]; }
            float umn = uval[0], umx = uval[0], smn = sval[0], smx = sval[0];
#pragma unroll
            for (int k = 1; k < 16; k++) {
                umn = fminf(umn, uval[k]); umx = fmaxf(umx, uval[k]);
                smn = fminf(smn, sval[k]); smx = fmaxf(smx, sval[k]);
            }
            float ue[30], se[30];
            float ustep = (umx - umn) / 29.0f, sstep = (smx - smn) / 29.0f;
            for (int m = 0; m < 30; m++) {
                ue[m] = __fadd_rn(__fmul_rn((float)m, ustep), umn);
                se[m] = __fadd_rn(__fmul_rn((float)m, sstep), smn);
            }
            ue[29] = umx; se[29] = smx;
            int lu[16], ls[16];
#pragma unroll
            for (int k = 0; k < 16; k++) {
                int c = 0, c2 = 0;
                for (int m = 0; m < 30; m++) {
                    c += (ue[m] <= uval[k]) ? 1 : 0;
                    c2 += (se[m] <= sval[k]) ? 1 : 0;
                }
                lu[k] = c; ls[k] = c2;
            }
            double mi = 0.0;
#pragma unroll
            for (int k = 0; k < 16; k++) {
                int cu = 0, cs2 = 0, cc = 0;
#pragma unroll
                for (int j = 0; j < 16; j++) {
                    int bu = (lu[j] == lu[k]) ? 1 : 0;
                    int bs = (ls[j] == ls[k]) ? 1 : 0;
                    cu += bu; cs2 += bs; cc += (bu & bs);
                }
                mi += log((double)(cc * 16) / ((double)cu * (double)cs2));
            }
            mis[t] = mi / 16.0;
        }
        __syncthreads();
        if (t == 0) {
            double mu = 0.0;
            for (int i = 0; i < 16; i++) mu += mis[i];
            atomicAdd((double*)(W + 72), mu);
        }
    } else {
        return;
    }

    __syncthreads();
    if (t == 0) {
        __threadfence();
        if (atomicAdd(W + 74, 1u) == 32u) {
            double mi2 = atomicAdd((double*)(W + 70), 0.0);
            double mus = atomicAdd((double*)(W + 72), 0.0);
            double lpt = ((const double*)(W + 68))[0] / (double)N;
            out[0] = (float)(lpt + 0.1 * mi2 - 0.05 * mus);
        }
    }
}

// =====================================================================
// Legacy multi-kernel path (round-3 structure) — fallback only.
// =====================================================================
__global__ void k_init(u32* W, int zero_words) {
    size_t g = (size_t)blockIdx.x * blockDim.x + threadIdx.x;
    size_t stride = (size_t)gridDim.x * blockDim.x;
    for (size_t i = g; i < (size_t)zero_words; i += stride) W[GH_OFF + i] = 0u;
}

__global__ __launch_bounds__(256, 4) void k_minmax(
    const float* __restrict__ yt, const float* __restrict__ yp,
    const float* __restrict__ uv, const float* __restrict__ sv,
    int N, float* __restrict__ pb)
{
    const float INF = __builtin_inff();
    float umn[4], umx[4], smn[4], smx[4];
#pragma unroll
    for (int k = 0; k < 4; k++) { umn[k] = INF; umx[k] = -INF; smn[k] = INF; smx[k] = -INF; }

    const int t = threadIdx.x;
    const int G = gridDim.x;
    size_t nv4 = (size_t)N * 4;
    size_t per = ((nv4 + (size_t)G * 256 - 1) / ((size_t)G * 256)) * 256;
    size_t beg = (size_t)blockIdx.x * per;
    size_t end = beg + per; if (end > nv4) end = nv4;
    const float4* u4 = (const float4*)uv;
    const float4* s4 = (const float4*)sv;

    auto accU = [&](float4 a) {
        umn[0] = fminf(umn[0], a.x); umx[0] = fmaxf(umx[0], a.x);
        umn[1] = fminf(umn[1], a.y); umx[1] = fmaxf(umx[1], a.y);
        umn[2] = fminf(umn[2], a.z); umx[2] = fmaxf(umx[2], a.z);
        umn[3] = fminf(umn[3], a.w); umx[3] = fmaxf(umx[3], a.w);
    };
    auto accS = [&](float4 b) {
        smn[0] = fminf(smn[0], b.x); smx[0] = fmaxf(smx[0], b.x);
        smn[1] = fminf(smn[1], b.y); smx[1] = fmaxf(smx[1], b.y);
        smn[2] = fminf(smn[2], b.z); smx[2] = fmaxf(smx[2], b.z);
        smn[3] = fminf(smn[3], b.w); smx[3] = fmaxf(smx[3], b.w);
    };

    float ymn = INF, ymx = -INF, lpt = 0.0f;
    {
        size_t n2 = (size_t)N >> 1;
        size_t gid = (size_t)blockIdx.x * 256 + t;
        size_t ystr = (size_t)G * 256;
        const float2* yp2 = (const float2*)yp;
        const float2* yt2 = (const float2*)yt;
        for (size_t q = gid; q < n2; q += ystr) {
            float2 a = yp2[q], b = yt2[q];
            ymn = fminf(ymn, fminf(a.x, a.y));
            ymx = fmaxf(ymx, fmaxf(a.x, a.y));
            lpt += fabsf(b.x - a.x) + fabsf(b.y - a.y);
        }
        if ((N & 1) && gid == 0) {
            float y = yp[N - 1];
            ymn = fminf(ymn, y); ymx = fmaxf(ymx, y);
            lpt += fabsf(yt[N - 1] - y);
        }
    }

    size_t i = beg + t;
    size_t nb = (end > beg) ? (end - beg) / 1024 : 0;
    if (nb) {
        float4 u0 = u4[i], u1 = u4[i + 256], u2 = u4[i + 512], u3 = u4[i + 768];
        float4 s0 = s4[i], s1 = s4[i + 256], s2 = s4[i + 512], s3 = s4[i + 768];
        i += 1024;
        for (size_t b = 1; b < nb; b++, i += 1024) {
            float4 a0 = u4[i], a1 = u4[i + 256], a2 = u4[i + 512], a3 = u4[i + 768];
            float4 b0 = s4[i], b1 = s4[i + 256], b2 = s4[i + 512], b3 = s4[i + 768];
            accU(u0); accU(u1); accU(u2); accU(u3);
            accS(s0); accS(s1); accS(s2); accS(s3);
            u0 = a0; u1 = a1; u2 = a2; u3 = a3;
            s0 = b0; s1 = b1; s2 = b2; s3 = b3;
        }
        accU(u0); accU(u1); accU(u2); accU(u3);
        accS(s0); accS(s1); accS(s2); accS(s3);
    }
    for (; i < end; i += 256) { accU(u4[i]); accS(s4[i]); }

#pragma unroll
    for (int m = 4; m < 64; m <<= 1) {
#pragma unroll
        for (int k = 0; k < 4; k++) {
            umn[k] = fminf(umn[k], __shfl_xor(umn[k], m));
            umx[k] = fmaxf(umx[k], __shfl_xor(umx[k], m));
            smn[k] = fminf(smn[k], __shfl_xor(smn[k], m));
            smx[k] = fmaxf(smx[k], __shfl_xor(smx[k], m));
        }
    }
#pragma unroll
    for (int m = 1; m < 64; m <<= 1) {
        ymn = fminf(ymn, __shfl_xor(ymn, m));
        ymx = fmaxf(ymx, __shfl_xor(ymx, m));
        lpt += __shfl_xor(lpt, m);
    }

    __shared__ float LUmn[64], LUmx[64], LSmn[64], LSmx[64];
    __shared__ float LY[4][3];
    int wave = threadIdx.x >> 6, lane = threadIdx.x & 63;
    if (lane < 4) {
#pragma unroll
        for (int k = 0; k < 4; k++) {
            LUmn[wave * 16 + lane * 4 + k] = umn[k];
            LUmx[wave * 16 + lane * 4 + k] = umx[k];
            LSmn[wave * 16 + lane * 4 + k] = smn[k];
            LSmx[wave * 16 + lane * 4 + k] = smx[k];
        }
    }
    if (lane == 0) { LY[wave][0] = ymn; LY[wave][1] = ymx; LY[wave][2] = lpt; }
    __syncthreads();
    int bid = blockIdx.x;
    if (threadIdx.x < 16) {
        int v = threadIdx.x;
        pb[(size_t)v * G + bid] =
            fminf(fminf(LUmn[v], LUmn[16 + v]), fminf(LUmn[32 + v], LUmn[48 + v]));
        pb[(size_t)(16 + v) * G + bid] =
            fminf(fminf(LSmn[v], LSmn[16 + v]), fminf(LSmn[32 + v], LSmn[48 + v]));
        pb[(size_t)(32 + v) * G + bid] =
            fmaxf(fmaxf(LUmx[v], LUmx[16 + v]), fmaxf(LUmx[32 + v], LUmx[48 + v]));
        pb[(size_t)(48 + v) * G + bid] =
            fmaxf(fmaxf(LSmx[v], LSmx[16 + v]), fmaxf(LSmx[32 + v], LSmx[48 + v]));
    } else if (threadIdx.x == 64) {
        pb[(size_t)64 * G + bid] = fminf(fminf(LY[0][0], LY[1][0]), fminf(LY[2][0], LY[3][0]));
        pb[(size_t)65 * G + bid] = fmaxf(fmaxf(LY[0][1], LY[1][1]), fmaxf(LY[2][1], LY[3][1]));
        pb[(size_t)66 * G + bid] = LY[0][2] + LY[1][2] + LY[2][2] + LY[3][2];
    }
}

__global__ __launch_bounds__(256) void k_reduce(const float* __restrict__ pb, int G, u32* W) {
    if (blockIdx.x == 0 && threadIdx.x == 0) {
        ((double*)(W + 70))[0] = 0.0;
        ((double*)(W + 72))[0] = 0.0;
        W[74] = 0u;
    }
    const float INF = __builtin_inff();
    int v = blockIdx.x;
    const float* src = pb + (size_t)v * G;
    int op = (v == 66) ? 2 : ((v < 32 || v == 64) ? 0 : 1);
    float acc = (op == 0) ? INF : -INF;
    double da = 0.0;
    for (int b = threadIdx.x; b < G; b += 256) {
        float x = src[b];
        if (op == 0) acc = fminf(acc, x);
        else if (op == 1) acc = fmaxf(acc, x);
        else da += (double)x;
    }
#pragma unroll
    for (int m = 1; m < 64; m <<= 1) {
        float o = __shfl_xor(acc, m);
        acc = (op == 0) ? fminf(acc, o) : fmaxf(acc, o);
        da += __shfl_xor(da, m);
    }
    __shared__ float sf[4];
    __shared__ double sd[4];
    int wave = threadIdx.x >> 6;
    if ((threadIdx.x & 63) == 0) { sf[wave] = acc; sd[wave] = da; }
    __syncthreads();
    if (threadIdx.x == 0) {
        float r = (op == 0) ? fminf(fminf(sf[0], sf[1]), fminf(sf[2], sf[3]))
                            : fmaxf(fmaxf(sf[0], sf[1]), fmaxf(sf[2], sf[3]));
        if (v == 66)      ((double*)(W + 68))[0] = sd[0] + sd[1] + sd[2] + sd[3];
        else if (v == 64) ((float*)W)[0] = r;
        else if (v == 65) ((float*)W)[1] = r;
        else              ((float*)W)[2 + v] = r;
    }
}

__global__ __launch_bounds__(512) void k_hist(
    const float* __restrict__ yp, const float* __restrict__ uv, const float* __restrict__ sv,
    int N, const u32* __restrict__ W, u32* __restrict__ gh, int copies)
{
    __shared__ u32 hist[PWORDS];
    __shared__ float ex[16][32];
    __shared__ float ey[32];
    __shared__ float emn[16], esc[16];
    __shared__ float yp0[2];
    int mat = blockIdx.y;
    const float* src = mat ? sv : uv;
    const float* Wf = (const float*)W;

    for (int i = threadIdx.x; i < PWORDS; i += 512) hist[i] = 0;
    if (threadIdx.x < 16) {
        int j = threadIdx.x;
        float mn = Wf[2 + mat * 16 + j];
        float mx = Wf[34 + mat * 16 + j];
        float step = (mx - mn) / 30.0f;
        for (int m = 0; m < 31; m++) ex[j][m] = __fadd_rn(__fmul_rn((float)m, step), mn);
        ex[j][30] = mx;
        emn[j] = mn;
        esc[j] = (mx > mn) ? 30.0f / (mx - mn) : 0.0f;
    } else if (threadIdx.x == 16) {
        float mn = Wf[0], mx = Wf[1];
        float step = (mx - mn) / 30.0f;
        for (int m = 0; m < 31; m++) ey[m] = __fadd_rn(__fmul_rn((float)m, step), mn);
        ey[30] = mx;
        yp0[0] = mn;
        yp0[1] = (mx > mn) ? 30.0f / (mx - mn) : 0.0f;
    }
    __syncthreads();

    float ymn = yp0[0], ysc = yp0[1];
    int rpb = (N + gridDim.x - 1) / gridDim.x;
    int r0 = blockIdx.x * rpb;
    int r1 = r0 + rpb; if (r1 > N) r1 = N;

    auto process = [&](float y, float4 q0, float4 q1, float4 q2, float4 q3) {
        int yb = (int)__fmul_rn(__fsub_rn(y, ymn), ysc);
        if (yb > 29) yb = 29;
        if (y < ey[yb]) yb--;
        if (yb != 29 && y >= ey[yb + 1]) yb++;
        float v[16] = {q0.x, q0.y, q0.z, q0.w, q1.x, q1.y, q1.z, q1.w,
                       q2.x, q2.y, q2.z, q2.w, q3.x, q3.y, q3.z, q3.w};
#pragma unroll
        for (int j = 0; j < 16; j++) {
            float vv = v[j];
            int b = (int)__fmul_rn(__fsub_rn(vv, emn[j]), esc[j]);
            if (b > 29) b = 29;
            if (vv < ex[j][b]) b--;
            if (b != 29 && vv >= ex[j][b + 1]) b++;
            u32 idx = (u32)(j * NCELL + b * NBINS + yb);
            atomicAdd(&hist[idx >> 1], 1u << ((idx & 1) * 16));
        }
    };

    int row = r0 + (int)threadIdx.x;
    if (row < r1) {
        const float4* p = (const float4*)(src + (size_t)row * 16);
        float4 c0 = p[0], c1 = p[1], c2 = p[2], c3 = p[3];
        float yc = yp[row];
        for (int nr = row + 512; nr < r1; nr += 512) {
            const float4* np = (const float4*)(src + (size_t)nr * 16);
            float4 d0 = np[0], d1 = np[1], d2 = np[2], d3 = np[3];
            float yn = yp[nr];
            process(yc, c0, c1, c2, c3);
            c0 = d0; c1 = d1; c2 = d2; c3 = d3; yc = yn;
        }
        process(yc, c0, c1, c2, c3);
    }
    __syncthreads();

    if (copies == (int)gridDim.x) {
        u32* dst = gh + ((size_t)blockIdx.x * 2 + mat) * PWORDS;
        for (int i = threadIdx.x; i < PWORDS; i += 512) dst[i] = hist[i];
    } else {
        u32* dst = gh + (((size_t)(blockIdx.x % copies)) * 2 + mat) * HWORDS;
        for (int i = threadIdx.x; i < PWORDS; i += 512) {
            u32 w = hist[i];
            u32 lo = w & 0xFFFFu, hi = w >> 16;
            if (lo) atomicAdd(&dst[2 * i], lo);
            if (hi) atomicAdd(&dst[2 * i + 1], hi);
        }
    }
}

__global__ __launch_bounds__(256) void k_sum1(
    const u32* __restrict__ gh, u32* __restrict__ part, int slots_per_cg)
{
    int f = blockIdx.x * 256 + threadIdx.x;
    if (f >= 2 * PWORDS) return;
    int cg = blockIdx.y;
    const u32* p = gh + (size_t)(cg * slots_per_cg) * (2 * PWORDS) + f;
    u32 lo0 = 0, hi0 = 0, lo1 = 0, hi1 = 0;
    int s = 0;
    for (; s + 3 < slots_per_cg; s += 4) {
        u32 w0 = p[(size_t)s * (2 * PWORDS)];
        u32 w1 = p[(size_t)(s + 1) * (2 * PWORDS)];
        u32 w2 = p[(size_t)(s + 2) * (2 * PWORDS)];
        u32 w3 = p[(size_t)(s + 3) * (2 * PWORDS)];
        lo0 += w0 & 0xFFFFu; hi0 += w0 >> 16;
        lo1 += w1 & 0xFFFFu; hi1 += w1 >> 16;
        lo0 += w2 & 0xFFFFu; hi0 += w2 >> 16;
        lo1 += w3 & 0xFFFFu; hi1 += w3 >> 16;
    }
    for (; s < slots_per_cg; s++) {
        u32 w = p[(size_t)s * (2 * PWORDS)];
        lo0 += w & 0xFFFFu; hi0 += w >> 16;
    }
    int mat = f / PWORDS, i = f - mat * PWORDS;
    u32* dst = part + (size_t)cg * (2 * HWORDS) + (size_t)mat * HWORDS + 2 * i;
    dst[0] = lo0 + lo1;
    dst[1] = hi0 + hi1;
}

__global__ __launch_bounds__(256) void k_sum(
    const u32* __restrict__ gh, u32* __restrict__ hs, int copies)
{
    int f = blockIdx.x * 256 + threadIdx.x;
    if (f >= 2 * HWORDS) return;
    u32 a = 0;
    const u32* p = gh + f;
    for (int s = 0; s < copies; s++) a += p[(size_t)s * (2 * HWORDS)];
    hs[f] = a;
}

__global__ __launch_bounds__(256) void k_mi_final(
    const u32* __restrict__ part, const u32* __restrict__ hs, int packed,
    const float* __restrict__ uv, const float* __restrict__ sv,
    int N, u32* W, float* out)
{
    int h = blockIdx.x;
    if (h < 32) {
        __shared__ float C[NCELL];
        __shared__ float rsums[NBINS], csums[NBINS];
        __shared__ double red[4];
        int mat = h >> 4, col = h & 15;
        if (packed) {
            const u32* src = part + (size_t)mat * HWORDS + (size_t)col * NCELL;
            for (int c = threadIdx.x; c < NCELL; c += 256) {
                u32 a = 0;
#pragma unroll
                for (int cg = 0; cg < CG; cg++) a += src[(size_t)cg * (2 * HWORDS) + c];
                C[c] = (float)a;
            }
        } else {
            const u32* src = hs + (size_t)mat * HWORDS + (size_t)col * NCELL;
            for (int c = threadIdx.x; c < NCELL; c += 256) C[c] = (float)src[c];
        }
        __syncthreads();
        if (threadIdx.x < NBINS) {
            float s = 0;
            for (int j = 0; j < NBINS; j++) s += C[threadIdx.x * NBINS + j];
            rsums[threadIdx.x] = s;
        } else if (threadIdx.x >= 32 && threadIdx.x < 32 + NBINS) {
            int j = threadIdx.x - 32;
            float s = 0;
            for (int i = 0; i < NBINS; i++) s += C[i * NBINS + j];
            csums[j] = s;
        }
        __syncthreads();

        const float n = (float)N;
        double acc = 0.0;
        for (int c = threadIdx.x; c < NCELL; c += 256) {
            int i = c / NBINS, j = c % NBINS;
            float pxy = (C[c] > 0.0f) ? (C[c] / n) : 1e-10f;
            float px = (rsums[i] > 0.0f) ? (rsums[i] / n) : 1e-10f;
            float py = (csums[j] > 0.0f) ? (csums[j] / n) : 1e-10f;
            acc += (double)(pxy * logf(pxy / (px * py)));
        }
#pragma unroll
        for (int o = 32; o > 0; o >>= 1) acc += __shfl_xor(acc, o);
        int wid = threadIdx.x >> 6;
        if ((threadIdx.x & 63) == 0) red[wid] = acc;
        __syncthreads();
        if (threadIdx.x == 0) {
            double tt = red[0] + red[1] + red[2] + red[3];
            atomicAdd((double*)(W + 70), tt);
        }
    } else {
        __shared__ double mis[16];
        int t = threadIdx.x;
        if (t < 16) {
            float uval[16], sval[16];
#pragma unroll
            for (int k = 0; k < 16; k++) { uval[k] = uv[t * 16 + k]; sval[k] = sv[t * 16 + k]; }
            float umn = uval[0], umx = uval[0], smn = sval[0], smx = sval[0];
#pragma unroll
            for (int k = 1; k < 16; k++) {
                umn = fminf(umn, uval[k]); umx = fmaxf(umx, uval[k]);
                smn = fminf(smn, sval[k]); smx = fmaxf(smx, sval[k]);
            }
            float ue[30], se[30];
            float ustep = (umx - umn) / 29.0f, sstep = (smx - smn) / 29.0f;
            for (int m = 0; m < 30; m++) {
                ue[m] = __fadd_rn(__fmul_rn((float)m, ustep), umn);
                se[m] = __fadd_rn(__fmul_rn((float)m, sstep), smn);
            }
            ue[29] = umx; se[29] = smx;
            int lu[16], ls[16];
#pragma unroll
            for (int k = 0; k < 16; k++) {
                int c = 0, c2 = 0;
                for (int m = 0; m < 30; m++) {
                    c += (ue[m] <= uval[k]) ? 1 : 0;
                    c2 += (se[m] <= sval[k]) ? 1 : 0;
                }
                lu[k] = c; ls[k] = c2;
            }
            double mi = 0.0;
#pragma unroll
            for (int k = 0; k < 16; k++) {
                int cu = 0, cs2 = 0, cc = 0;
#pragma unroll
                for (int j = 0; j < 16; j++) {
                    int bu = (lu[j] == lu[k]) ? 1 : 0;
                    int bs = (ls[j] == ls[k]) ? 1 : 0;
                    cu += bu; cs2 += bs; cc += (bu & bs);
                }
                mi += log((double)(cc * 16) / ((double)cu * (double)cs2));
            }
            mis[t] = mi / 16.0;
        }
        __syncthreads();
        if (t == 0) {
            double mu = 0.0;
            for (int i = 0; i < 16; i++) mu += mis[i];
            atomicAdd((double*)(W + 72), mu);
        }
    }

    __syncthreads();
    if (threadIdx.x == 0) {
        __threadfence();
        u32 old = atomicAdd(W + 74, 1u);
        if (old == 32u) {
            double mi2 = atomicAdd((double*)(W + 70), 0.0);
            double mus = atomicAdd((double*)(W + 72), 0.0);
            double lpt = ((const double*)(W + 68))[0] / (double)N;
            out[0] = (float)(lpt + 0.1 * mi2 - 0.05 * mus);
        }
    }
}

extern "C" void kernel_launch(void* const* d_in, const int* in_sizes, int n_in,
                              void* d_out, int out_size, void* d_ws, size_t ws_size,
                              hipStream_t stream)
{
    int N = in_sizes[0];
    const float* yt = (const float*)d_in[0];
    const float* yp = (const float*)d_in[1];
    const float* uv = (const float*)d_in[4];
    const float* sv = (const float*)d_in[5];
    u32* W = (u32*)d_ws;
    float* pb = (float*)(W + PB_OFF);
    u32* hs = W + HS_OFF;
    u32* gh = W + GH_OFF;
    float* outp = (float*)d_out;

    size_t slots_words = (size_t)NCH * 2 * PWORDS;
    size_t part_words = (size_t)CG * 2 * HWORDS;
    size_t avail_words = (ws_size / 4 > (size_t)GH_OFF) ? ws_size / 4 - GH_OFF : 0;
    int copies, zero_words, packed;
    if (avail_words >= slots_words + part_words) {
        copies = NCH; packed = 1; zero_words = 0;
    } else {
        long c = (long)(avail_words / (2 * HWORDS));
        copies = (c < 1) ? 1 : ((c > 8) ? 8 : (int)c);
        packed = 0;
        zero_words = copies * 2 * HWORDS;
    }
    u32* part = gh + slots_words;

    // one-time: cooperative-launch capability + co-resident grid size
    static int coop_grid = -2;
    if (coop_grid == -2) {
        int g = 0;
        int dev = 0;
        if (hipGetDevice(&dev) == hipSuccess) {
            int sup = 0;
            hipDeviceGetAttribute(&sup, hipDeviceAttributeCooperativeLaunch, dev);
            if (sup) {
                hipDeviceProp_t prop;
                if (hipGetDeviceProperties(&prop, dev) == hipSuccess) {
                    int nb = 0;
                    if (hipOccupancyMaxActiveBlocksPerMultiprocessor(&nb, k_all, 512, 0)
                            == hipSuccess && nb > 0) {
                        long cap = (long)nb * prop.multiProcessorCount;
                        long want = cap < 1024 ? cap : 1024;
                        want &= ~31L;               // nch multiple of 16 (CG divisibility)
                        if (want >= 64) g = (int)want;
                    }
                }
            }
        }
        coop_grid = g;
    }

    if (packed && coop_grid > 0) {
        k_init0<<<dim3(1), dim3(512), 0, stream>>>(W);
        void* args[] = { (void*)&yt, (void*)&yp, (void*)&uv, (void*)&sv,
                         (void*)&N, (void*)&W, (void*)&gh, (void*)&part, (void*)&outp };
        hipLaunchCooperativeKernel(reinterpret_cast<void*>(k_all),
                                   dim3(coop_grid), dim3(512), args, 0, stream);
        return;
    }

    // legacy multi-kernel path
    if (!packed)
        k_init<<<dim3(120), dim3(512), 0, stream>>>(W, zero_words);
    k_minmax<<<dim3(G_MM), dim3(256), 0, stream>>>(yt, yp, uv, sv, N, pb);
    k_reduce<<<dim3(67), dim3(256), 0, stream>>>(pb, G_MM, W);
    k_hist<<<dim3(NCH, 2), dim3(512), 0, stream>>>(yp, uv, sv, N, W, gh, copies);
    if (packed) {
        k_sum1<<<dim3((2 * PWORDS + 255) / 256, CG), dim3(256), 0, stream>>>(gh, part, NCH / CG);
    } else {
        k_sum<<<dim3((2 * HWORDS + 255) / 256), dim3(256), 0, stream>>>(gh, hs, copies);
    }
    k_mi_final<<<dim3(33), dim3(256), 0, stream>>>(part, hs, packed, uv, sv, N, W, outp);
}

// Round 7
// 235.833 us; speedup vs baseline: 1.3447x; 1.3447x over previous
//
#include <hip/hip_runtime.h>

#define NBINS 30
#define NCELL 900            // 30*30
#define HWORDS (16*NCELL)    // 14400 cells per matrix histogram set
#define PWORDS (HWORDS/2)    // 7200 packed u32 (2 x u16 cells) per matrix
#define G_MM  2048           // k_minmax grid
#define NCH   512            // k_hist chunks per matrix (packed slot count)
#define CG    8              // copy-groups for two-stage slot merge (512/8=64 slots each)

typedef unsigned int u32;

// ws u32 layout:
//  [0] ymin (f32)  [1] ymax (f32)
//  [2..17] umin  [18..33] smin  [34..49] umax  [50..65] smax   (plain f32)
//  [68..69] double lpt_sum   [70..71] double mi2d_sum
//  [72..73] double mi_us_sum [74] finalize counter
//  [PB_OFF .. PB_OFF+68*G_MM)   : k_minmax partials, value-major pb[v*G_MM + b]
//  [HS_OFF .. HS_OFF+2*HWORDS)  : summed histograms {u,s} (fallback path only)
//  [GH_OFF ..]                  : hist slots: packed NCH x {u:7200, s:7200}
//                                 or fallback unpacked copies x {u:14400, s:14400}
//  packed mode only: [PT ..]     : stage-1 partials CG x 28800 u32
#define PB_OFF 128
#define HS_OFF (PB_OFF + 68*G_MM)
#define GH_OFF (HS_OFF + 2*HWORDS)

// fallback-only: zero unpacked histogram copies
__global__ void k_init(u32* W, int zero_words) {
    size_t g = (size_t)blockIdx.x * blockDim.x + threadIdx.x;
    size_t stride = (size_t)gridDim.x * blockDim.x;
    for (size_t i = g; i < (size_t)zero_words; i += stride) W[GH_OFF + i] = 0u;
}

// ---------- pass 1: per-column min/max + y min/max + L_PT (NO atomics) ----------
// Interleaved u+s, 8 float4 loads in flight, disjoint accumulator sets.
// Measured 47.3-47.7 us (round 3), the fastest variant tested.
__global__ __launch_bounds__(256, 4) void k_minmax(
    const float* __restrict__ yt, const float* __restrict__ yp,
    const float* __restrict__ uv, const float* __restrict__ sv,
    int N, float* __restrict__ pb)
{
    const float INF = __builtin_inff();
    float umn[4], umx[4], smn[4], smx[4];
#pragma unroll
    for (int k = 0; k < 4; k++) { umn[k] = INF; umx[k] = -INF; smn[k] = INF; smx[k] = -INF; }

    const int t = threadIdx.x;
    const int G = gridDim.x;
    size_t nv4 = (size_t)N * 4;  // 16 floats/row => 4 float4 per row
    size_t per = ((nv4 + (size_t)G * 256 - 1) / ((size_t)G * 256)) * 256;
    size_t beg = (size_t)blockIdx.x * per;
    size_t end = beg + per; if (end > nv4) end = nv4;
    const float4* u4 = (const float4*)uv;
    const float4* s4 = (const float4*)sv;

    auto accU = [&](float4 a) {
        umn[0] = fminf(umn[0], a.x); umx[0] = fmaxf(umx[0], a.x);
        umn[1] = fminf(umn[1], a.y); umx[1] = fmaxf(umx[1], a.y);
        umn[2] = fminf(umn[2], a.z); umx[2] = fmaxf(umx[2], a.z);
        umn[3] = fminf(umn[3], a.w); umx[3] = fmaxf(umx[3], a.w);
    };
    auto accS = [&](float4 b) {
        smn[0] = fminf(smn[0], b.x); smx[0] = fmaxf(smx[0], b.x);
        smn[1] = fminf(smn[1], b.y); smx[1] = fmaxf(smx[1], b.y);
        smn[2] = fminf(smn[2], b.z); smx[2] = fmaxf(smx[2], b.z);
        smn[3] = fminf(smn[3], b.w); smx[3] = fmaxf(smx[3], b.w);
    };

    // ---- y phase: float2 granularity -> exactly one pair per thread at N=2^20
    float ymn = INF, ymx = -INF, lpt = 0.0f;
    {
        size_t n2 = (size_t)N >> 1;
        size_t gid = (size_t)blockIdx.x * 256 + t;
        size_t ystr = (size_t)G * 256;
        const float2* yp2 = (const float2*)yp;
        const float2* yt2 = (const float2*)yt;
        for (size_t q = gid; q < n2; q += ystr) {
            float2 a = yp2[q], b = yt2[q];
            ymn = fminf(ymn, fminf(a.x, a.y));
            ymx = fmaxf(ymx, fmaxf(a.x, a.y));
            lpt += fabsf(b.x - a.x) + fabsf(b.y - a.y);
        }
        if ((N & 1) && gid == 0) {
            float y = yp[N - 1];
            ymn = fminf(ymn, y); ymx = fmaxf(ymx, y);
            lpt += fabsf(yt[N - 1] - y);
        }
    }

    // ---- u+s interleaved, 8 loads in flight, disjoint accumulator sets ----
    size_t i = beg + t;
    size_t nb = (end > beg) ? (end - beg) / 1024 : 0;   // 4-float4-per-thread batches
    if (nb) {
        float4 u0 = u4[i], u1 = u4[i + 256], u2 = u4[i + 512], u3 = u4[i + 768];
        float4 s0 = s4[i], s1 = s4[i + 256], s2 = s4[i + 512], s3 = s4[i + 768];
        i += 1024;
        for (size_t b = 1; b < nb; b++, i += 1024) {
            float4 a0 = u4[i], a1 = u4[i + 256], a2 = u4[i + 512], a3 = u4[i + 768];
            float4 b0 = s4[i], b1 = s4[i + 256], b2 = s4[i + 512], b3 = s4[i + 768];
            accU(u0); accU(u1); accU(u2); accU(u3);
            accS(s0); accS(s1); accS(s2); accS(s3);
            u0 = a0; u1 = a1; u2 = a2; u3 = a3;
            s0 = b0; s1 = b1; s2 = b2; s3 = b3;
        }
        accU(u0); accU(u1); accU(u2); accU(u3);
        accS(s0); accS(s1); accS(s2); accS(s3);
    }
    for (; i < end; i += 256) { accU(u4[i]); accS(s4[i]); }

    // wave reduce: column classes keyed by lane&3
#pragma unroll
    for (int m = 4; m < 64; m <<= 1) {
#pragma unroll
        for (int k = 0; k < 4; k++) {
            umn[k] = fminf(umn[k], __shfl_xor(umn[k], m));
            umx[k] = fmaxf(umx[k], __shfl_xor(umx[k], m));
            smn[k] = fminf(smn[k], __shfl_xor(smn[k], m));
            smx[k] = fmaxf(smx[k], __shfl_xor(smx[k], m));
        }
    }
#pragma unroll
    for (int m = 1; m < 64; m <<= 1) {
        ymn = fminf(ymn, __shfl_xor(ymn, m));
        ymx = fmaxf(ymx, __shfl_xor(ymx, m));
        lpt += __shfl_xor(lpt, m);
    }

    __shared__ float LUmn[64], LUmx[64], LSmn[64], LSmx[64];
    __shared__ float LY[4][3];
    int wave = threadIdx.x >> 6, lane = threadIdx.x & 63;
    if (lane < 4) {
#pragma unroll
        for (int k = 0; k < 4; k++) {
            LUmn[wave * 16 + lane * 4 + k] = umn[k];
            LUmx[wave * 16 + lane * 4 + k] = umx[k];
            LSmn[wave * 16 + lane * 4 + k] = smn[k];
            LSmx[wave * 16 + lane * 4 + k] = smx[k];
        }
    }
    if (lane == 0) { LY[wave][0] = ymn; LY[wave][1] = ymx; LY[wave][2] = lpt; }
    __syncthreads();
    int bid = blockIdx.x;
    if (threadIdx.x < 16) {
        int v = threadIdx.x;
        pb[(size_t)v * G + bid] =
            fminf(fminf(LUmn[v], LUmn[16 + v]), fminf(LUmn[32 + v], LUmn[48 + v]));
        pb[(size_t)(16 + v) * G + bid] =
            fminf(fminf(LSmn[v], LSmn[16 + v]), fminf(LSmn[32 + v], LSmn[48 + v]));
        pb[(size_t)(32 + v) * G + bid] =
            fmaxf(fmaxf(LUmx[v], LUmx[16 + v]), fmaxf(LUmx[32 + v], LUmx[48 + v]));
        pb[(size_t)(48 + v) * G + bid] =
            fmaxf(fmaxf(LSmx[v], LSmx[16 + v]), fmaxf(LSmx[32 + v], LSmx[48 + v]));
    } else if (threadIdx.x == 64) {
        pb[(size_t)64 * G + bid] = fminf(fminf(LY[0][0], LY[1][0]), fminf(LY[2][0], LY[3][0]));
        pb[(size_t)65 * G + bid] = fmaxf(fmaxf(LY[0][1], LY[1][1]), fmaxf(LY[2][1], LY[3][1]));
        pb[(size_t)66 * G + bid] = LY[0][2] + LY[1][2] + LY[2][2] + LY[3][2];
    }
}

// ---------- collapse partials -> W (67 blocks); also zero accumulators ----------
__global__ __launch_bounds__(256) void k_reduce(const float* __restrict__ pb, int G, u32* W) {
    if (blockIdx.x == 0 && threadIdx.x == 0) {
        ((double*)(W + 70))[0] = 0.0;   // mi2d accumulator
        ((double*)(W + 72))[0] = 0.0;   // mi_us accumulator
        W[74] = 0u;                     // finalize counter
    }
    const float INF = __builtin_inff();
    int v = blockIdx.x;                      // 0..66
    const float* src = pb + (size_t)v * G;
    int op = (v == 66) ? 2 : ((v < 32 || v == 64) ? 0 : 1);   // 0=min 1=max 2=sum
    float acc = (op == 0) ? INF : -INF;
    double da = 0.0;
    for (int b = threadIdx.x; b < G; b += 256) {
        float x = src[b];
        if (op == 0) acc = fminf(acc, x);
        else if (op == 1) acc = fmaxf(acc, x);
        else da += (double)x;
    }
#pragma unroll
    for (int m = 1; m < 64; m <<= 1) {
        float o = __shfl_xor(acc, m);
        acc = (op == 0) ? fminf(acc, o) : fmaxf(acc, o);
        da += __shfl_xor(da, m);
    }
    __shared__ float sf[4];
    __shared__ double sd[4];
    int wave = threadIdx.x >> 6;
    if ((threadIdx.x & 63) == 0) { sf[wave] = acc; sd[wave] = da; }
    __syncthreads();
    if (threadIdx.x == 0) {
        float r = (op == 0) ? fminf(fminf(sf[0], sf[1]), fminf(sf[2], sf[3]))
                            : fmaxf(fmaxf(sf[0], sf[1]), fmaxf(sf[2], sf[3]));
        if (v == 66)      ((double*)(W + 68))[0] = sd[0] + sd[1] + sd[2] + sd[3];
        else if (v == 64) ((float*)W)[0] = r;
        else if (v == 65) ((float*)W)[1] = r;
        else              ((float*)W)[2 + v] = r;
    }
}

// ---------- pass 2: 2-D histograms, u16-packed LDS, np.histogram-exact binning ----------
// Row-level software pipeline: next row's 4xfloat4 + y in flight during the
// current row's binning + 16 LDS atomics.
__global__ __launch_bounds__(512) void k_hist(
    const float* __restrict__ yp, const float* __restrict__ uv, const float* __restrict__ sv,
    int N, const u32* __restrict__ W, u32* __restrict__ gh, int copies)
{
    __shared__ u32 hist[PWORDS];   // 14400 u16 cells packed into 7200 u32
    __shared__ float ex[16][32];   // 31 edges per col (+pad)
    __shared__ float ey[32];
    __shared__ float emn[16], esc[16];
    __shared__ float yp0[2];       // ymn, ysc
    int mat = blockIdx.y;
    const float* src = mat ? sv : uv;
    const float* Wf = (const float*)W;

    for (int i = threadIdx.x; i < PWORDS; i += 512) hist[i] = 0;
    if (threadIdx.x < 16) {
        int j = threadIdx.x;
        float mn = Wf[2 + mat * 16 + j];
        float mx = Wf[34 + mat * 16 + j];
        float step = (mx - mn) / 30.0f;
        for (int m = 0; m < 31; m++) ex[j][m] = __fadd_rn(__fmul_rn((float)m, step), mn);
        ex[j][30] = mx;            // np.linspace endpoint
        emn[j] = mn;
        esc[j] = (mx > mn) ? 30.0f / (mx - mn) : 0.0f;
    } else if (threadIdx.x == 16) {
        float mn = Wf[0], mx = Wf[1];
        float step = (mx - mn) / 30.0f;
        for (int m = 0; m < 31; m++) ey[m] = __fadd_rn(__fmul_rn((float)m, step), mn);
        ey[30] = mx;
        yp0[0] = mn;
        yp0[1] = (mx > mn) ? 30.0f / (mx - mn) : 0.0f;
    }
    __syncthreads();

    float ymn = yp0[0], ysc = yp0[1];
    int rpb = (N + gridDim.x - 1) / gridDim.x;
    int r0 = blockIdx.x * rpb;
    int r1 = r0 + rpb; if (r1 > N) r1 = N;

    auto process = [&](float y, float4 q0, float4 q1, float4 q2, float4 q3) {
        int yb = (int)__fmul_rn(__fsub_rn(y, ymn), ysc);
        if (yb > 29) yb = 29;
        if (y < ey[yb]) yb--;
        if (yb != 29 && y >= ey[yb + 1]) yb++;
        float v[16] = {q0.x, q0.y, q0.z, q0.w, q1.x, q1.y, q1.z, q1.w,
                       q2.x, q2.y, q2.z, q2.w, q3.x, q3.y, q3.z, q3.w};
#pragma unroll
        for (int j = 0; j < 16; j++) {
            float vv = v[j];
            int b = (int)__fmul_rn(__fsub_rn(vv, emn[j]), esc[j]);
            if (b > 29) b = 29;
            if (vv < ex[j][b]) b--;
            if (b != 29 && vv >= ex[j][b + 1]) b++;
            u32 idx = (u32)(j * NCELL + b * NBINS + yb);
            atomicAdd(&hist[idx >> 1], 1u << ((idx & 1) * 16));
        }
    };

    int row = r0 + (int)threadIdx.x;
    if (row < r1) {
        const float4* p = (const float4*)(src + (size_t)row * 16);
        float4 c0 = p[0], c1 = p[1], c2 = p[2], c3 = p[3];
        float yc = yp[row];
        for (int nr = row + 512; nr < r1; nr += 512) {
            const float4* np = (const float4*)(src + (size_t)nr * 16);
            float4 d0 = np[0], d1 = np[1], d2 = np[2], d3 = np[3];
            float yn = yp[nr];
            process(yc, c0, c1, c2, c3);
            c0 = d0; c1 = d1; c2 = d2; c3 = d3; yc = yn;
        }
        process(yc, c0, c1, c2, c3);
    }
    __syncthreads();

    if (copies == (int)gridDim.x) {
        // packed private slot: plain coalesced stores, no atomics
        u32* dst = gh + ((size_t)blockIdx.x * 2 + mat) * PWORDS;
        for (int i = threadIdx.x; i < PWORDS; i += 512) dst[i] = hist[i];
    } else {
        // fallback: unpack and atomically accumulate into unpacked copies
        u32* dst = gh + (((size_t)(blockIdx.x % copies)) * 2 + mat) * HWORDS;
        for (int i = threadIdx.x; i < PWORDS; i += 512) {
            u32 w = hist[i];
            u32 lo = w & 0xFFFFu, hi = w >> 16;
            if (lo) atomicAdd(&dst[2 * i], lo);
            if (hi) atomicAdd(&dst[2 * i + 1], hi);
        }
    }
}

// ---------- stage 1: sum 64 slots per copy-group (packed path) ----------
// grid (57, 8) = 456 always-active blocks (round-1 config, best total measured)
__global__ __launch_bounds__(256) void k_sum1(
    const u32* __restrict__ gh, u32* __restrict__ part, int slots_per_cg)
{
    int f = blockIdx.x * 256 + threadIdx.x;
    if (f >= 2 * PWORDS) return;
    int cg = blockIdx.y;
    const u32* p = gh + (size_t)(cg * slots_per_cg) * (2 * PWORDS) + f;
    u32 lo0 = 0, hi0 = 0, lo1 = 0, hi1 = 0;
    int s = 0;
    for (; s + 3 < slots_per_cg; s += 4) {
        u32 w0 = p[(size_t)s * (2 * PWORDS)];
        u32 w1 = p[(size_t)(s + 1) * (2 * PWORDS)];
        u32 w2 = p[(size_t)(s + 2) * (2 * PWORDS)];
        u32 w3 = p[(size_t)(s + 3) * (2 * PWORDS)];
        lo0 += w0 & 0xFFFFu; hi0 += w0 >> 16;
        lo1 += w1 & 0xFFFFu; hi1 += w1 >> 16;
        lo0 += w2 & 0xFFFFu; hi0 += w2 >> 16;
        lo1 += w3 & 0xFFFFu; hi1 += w3 >> 16;
    }
    for (; s < slots_per_cg; s++) {
        u32 w = p[(size_t)s * (2 * PWORDS)];
        lo0 += w & 0xFFFFu; hi0 += w >> 16;
    }
    int mat = f / PWORDS, i = f - mat * PWORDS;
    u32* dst = part + (size_t)cg * (2 * HWORDS) + (size_t)mat * HWORDS + 2 * i;
    dst[0] = lo0 + lo1;
    dst[1] = hi0 + hi1;
}

// ---------- fallback merge (unpacked copies <= 8) ----------
__global__ __launch_bounds__(256) void k_sum(
    const u32* __restrict__ gh, u32* __restrict__ hs, int copies)
{
    int f = blockIdx.x * 256 + threadIdx.x;
    if (f >= 2 * HWORDS) return;
    u32 a = 0;
    const u32* p = gh + f;
    for (int s = 0; s < copies; s++) a += p[(size_t)s * (2 * HWORDS)];
    hs[f] = a;
}

// ---------- fused: stage-2 sum + per-histogram MI + mi_us + final combine ----------
// blocks 0..31: one histogram each (sums CG partials inline in packed mode)
// block 32:     mi_us on first 16 rows
// last block to finish writes the output (threadfence + atomic counter).
__global__ __launch_bounds__(256) void k_mi_final(
    const u32* __restrict__ part, const u32* __restrict__ hs, int packed,
    const float* __restrict__ uv, const float* __restrict__ sv,
    int N, u32* W, float* out)
{
    int h = blockIdx.x;
    if (h < 32) {
        __shared__ float C[NCELL];
        __shared__ float rsums[NBINS], csums[NBINS];
        __shared__ double red[4];
        int mat = h >> 4, col = h & 15;
        if (packed) {
            const u32* src = part + (size_t)mat * HWORDS + (size_t)col * NCELL;
            for (int c = threadIdx.x; c < NCELL; c += 256) {
                u32 a = 0;
#pragma unroll
                for (int cg = 0; cg < CG; cg++) a += src[(size_t)cg * (2 * HWORDS) + c];
                C[c] = (float)a;
            }
        } else {
            const u32* src = hs + (size_t)mat * HWORDS + (size_t)col * NCELL;
            for (int c = threadIdx.x; c < NCELL; c += 256) C[c] = (float)src[c];
        }
        __syncthreads();
        if (threadIdx.x < NBINS) {
            float s = 0;
            for (int j = 0; j < NBINS; j++) s += C[threadIdx.x * NBINS + j];
            rsums[threadIdx.x] = s;
        } else if (threadIdx.x >= 32 && threadIdx.x < 32 + NBINS) {
            int j = threadIdx.x - 32;
            float s = 0;
            for (int i = 0; i < NBINS; i++) s += C[i * NBINS + j];
            csums[j] = s;
        }
        __syncthreads();

        const float n = (float)N;
        double acc = 0.0;
        for (int c = threadIdx.x; c < NCELL; c += 256) {
            int i = c / NBINS, j = c % NBINS;
            float pxy = (C[c] > 0.0f) ? (C[c] / n) : 1e-10f;
            float px  = (rsums[i] > 0.0f) ? (rsums[i] / n) : 1e-10f;
            float py  = (csums[j] > 0.0f) ? (csums[j] / n) : 1e-10f;
            acc += (double)(pxy * logf(pxy / (px * py)));
        }
#pragma unroll
        for (int o = 32; o > 0; o >>= 1) acc += __shfl_xor(acc, o);
        int wid = threadIdx.x >> 6;
        if ((threadIdx.x & 63) == 0) red[wid] = acc;
        __syncthreads();
        if (threadIdx.x == 0) {
            double tt = red[0] + red[1] + red[2] + red[3];
            atomicAdd((double*)(W + 70), tt);
        }
    } else {
        // mi_us on first 16 rows of uv/sv
        __shared__ double mis[16];
        int t = threadIdx.x;
        if (t < 16) {
            float uval[16], sval[16];
#pragma unroll
            for (int k = 0; k < 16; k++) { uval[k] = uv[t * 16 + k]; sval[k] = sv[t * 16 + k]; }
            float umn = uval[0], umx = uval[0], smn = sval[0], smx = sval[0];
#pragma unroll
            for (int k = 1; k < 16; k++) {
                umn = fminf(umn, uval[k]); umx = fmaxf(umx, uval[k]);
                smn = fminf(smn, sval[k]); smx = fmaxf(smx, sval[k]);
            }
            float ue[30], se[30];
            float ustep = (umx - umn) / 29.0f, sstep = (smx - smn) / 29.0f;
            for (int m = 0; m < 30; m++) {
                ue[m] = __fadd_rn(__fmul_rn((float)m, ustep), umn);
                se[m] = __fadd_rn(__fmul_rn((float)m, sstep), smn);
            }
            ue[29] = umx; se[29] = smx;
            int lu[16], ls[16];
#pragma unroll
            for (int k = 0; k < 16; k++) {
                int c = 0, c2 = 0;
                for (int m = 0; m < 30; m++) {
                    c  += (ue[m] <= uval[k]) ? 1 : 0;
                    c2 += (se[m] <= sval[k]) ? 1 : 0;
                }
                lu[k] = c; ls[k] = c2;
            }
            double mi = 0.0;
#pragma unroll
            for (int k = 0; k < 16; k++) {
                int cu = 0, cs2 = 0, cc = 0;
#pragma unroll
                for (int j = 0; j < 16; j++) {
                    int bu = (lu[j] == lu[k]) ? 1 : 0;
                    int bs = (ls[j] == ls[k]) ? 1 : 0;
                    cu += bu; cs2 += bs; cc += (bu & bs);
                }
                mi += log((double)(cc * 16) / ((double)cu * (double)cs2));
            }
            mis[t] = mi / 16.0;
        }
        __syncthreads();
        if (t == 0) {
            double mu = 0.0;
            for (int i = 0; i < 16; i++) mu += mis[i];
            atomicAdd((double*)(W + 72), mu);
        }
    }

    // finalize: last of the 33 blocks combines and writes the scalar output
    __syncthreads();
    if (threadIdx.x == 0) {
        __threadfence();
        u32 old = atomicAdd(W + 74, 1u);
        if (old == 32u) {
            double mi2 = atomicAdd((double*)(W + 70), 0.0);
            double mus = atomicAdd((double*)(W + 72), 0.0);
            double lpt = ((const double*)(W + 68))[0] / (double)N;
            out[0] = (float)(lpt + 0.1 * mi2 - 0.05 * mus);
        }
    }
}

extern "C" void kernel_launch(void* const* d_in, const int* in_sizes, int n_in,
                              void* d_out, int out_size, void* d_ws, size_t ws_size,
                              hipStream_t stream)
{
    int N = in_sizes[0];
    const float* yt = (const float*)d_in[0];
    const float* yp = (const float*)d_in[1];
    const float* uv = (const float*)d_in[4];
    const float* sv = (const float*)d_in[5];
    u32* W = (u32*)d_ws;
    float* pb = (float*)(W + PB_OFF);
    u32* hs = W + HS_OFF;
    u32* gh = W + GH_OFF;

    // packed mode needs slots + stage-1 partials
    size_t slots_words = (size_t)NCH * 2 * PWORDS;        // 7.37M words
    size_t part_words  = (size_t)CG * 2 * HWORDS;         // 230400 words
    size_t avail_words = (ws_size / 4 > (size_t)GH_OFF) ? ws_size / 4 - GH_OFF : 0;
    int copies, zero_words, packed;
    if (avail_words >= slots_words + part_words) {
        copies = NCH; packed = 1; zero_words = 0;
    } else {
        long c = (long)(avail_words / (2 * HWORDS));
        copies = (c < 1) ? 1 : ((c > 8) ? 8 : (int)c);
        packed = 0;
        zero_words = copies * 2 * HWORDS;
    }
    u32* part = gh + slots_words;

    if (!packed)
        k_init<<<dim3(120), dim3(512), 0, stream>>>(W, zero_words);
    k_minmax<<<dim3(G_MM), dim3(256), 0, stream>>>(yt, yp, uv, sv, N, pb);
    k_reduce<<<dim3(67), dim3(256), 0, stream>>>(pb, G_MM, W);
    k_hist<<<dim3(NCH, 2), dim3(512), 0, stream>>>(yp, uv, sv, N, W, gh, copies);
    if (packed) {
        k_sum1<<<dim3((2 * PWORDS + 255) / 256, CG), dim3(256), 0, stream>>>(gh, part, NCH / CG);
    } else {
        k_sum<<<dim3((2 * HWORDS + 255) / 256), dim3(256), 0, stream>>>(gh, hs, copies);
    }
    k_mi_final<<<dim3(33), dim3(256), 0, stream>>>(part, hs, packed, uv, sv, N, W, (float*)d_out);
}